// Round 13
// baseline (106.453 us; speedup 1.0000x reference)
//
#include <hip/hip_runtime.h>
#include <hip/hip_bf16.h>

#define B_    8
#define N_    9225
#define M_    4096
#define K_    32
#define HID_  64
#define DOUT_ 16

typedef __attribute__((ext_vector_type(8))) short short8;
typedef __attribute__((ext_vector_type(4))) float floatx4;
typedef __attribute__((ext_vector_type(2))) float f32x2;

static __device__ __forceinline__ short f2bf(float f) {
    __hip_bfloat16 h = __float2bfloat16(f);
    return __builtin_bit_cast(short, h);
}
static __device__ __forceinline__ f32x2 splat2(float v) { return (f32x2){v, v}; }
static __device__ __forceinline__ int bpermi(int src_bytes, int v) {
    return __builtin_amdgcn_ds_bpermute(src_bytes, v);
}
static __device__ __forceinline__ float bpermf(int src_bytes, float v) {
    return __builtin_bit_cast(float,
        __builtin_amdgcn_ds_bpermute(src_bytes, __builtin_bit_cast(int, v)));
}

// Sum over each 16-lane DPP row via row_shr tree; lane (row*16+15) holds the sum.
static __device__ __forceinline__ float row16_sum(float v) {
    int t;
    t = __builtin_amdgcn_update_dpp(0, __builtin_bit_cast(int, v), 0x111, 0xF, 0xF, true);
    v += __builtin_bit_cast(float, t);
    t = __builtin_amdgcn_update_dpp(0, __builtin_bit_cast(int, v), 0x112, 0xF, 0xF, true);
    v += __builtin_bit_cast(float, t);
    t = __builtin_amdgcn_update_dpp(0, __builtin_bit_cast(int, v), 0x114, 0xF, 0xF, true);
    v += __builtin_bit_cast(float, t);
    t = __builtin_amdgcn_update_dpp(0, __builtin_bit_cast(int, v), 0x118, 0xF, 0xF, true);
    v += __builtin_bit_cast(float, t);
    return v;
}

// gelu(x) ~ 0.5*x*(1 + tanh(z)), z = x*(0.79788456 + 0.035677408*x^2),
// tanh via Pade(5,4), clamped to [-1,1]. No v_exp. (Validated R4-R12.)
static __device__ __forceinline__ f32x2 gelu2(f32x2 x) {
    const f32x2 xsq = x * x;
    const f32x2 t   = __builtin_elementwise_fma(xsq, splat2(0.035677408f), splat2(0.79788456f));
    const f32x2 z   = x * t;
    const f32x2 u   = z * z;
    const f32x2 a   = u + splat2(105.0f);
    const f32x2 nin = __builtin_elementwise_fma(u, a, splat2(945.0f));
    const f32x2 num = z * nin;
    const f32x2 bq  = __builtin_elementwise_fma(u, splat2(15.0f), splat2(420.0f));
    const f32x2 den = __builtin_elementwise_fma(u, bq, splat2(945.0f));
    const f32x2 r   = { __builtin_amdgcn_rcpf(den[0]), __builtin_amdgcn_rcpf(den[1]) };
    f32x2 th = num * r;
    th = __builtin_elementwise_min(__builtin_elementwise_max(th, splat2(-1.0f)), splat2(1.0f));
    const f32x2 hx = x * splat2(0.5f);
    return __builtin_elementwise_fma(hx, th, hx);
}

// DOUBLE-MFMA version: BOTH MLP layers on matrix cores.
//   MFMA-1 (x4 tiles): H[64hid x 16nbr] = W1'[64 x 32K] x agg[32K x 16nbr],
//     agg cols = (y.x,y.y,x.x,x.y,1,0..) per neighbor (b1 folded at k=4;
//     only q=0 lanes hold nonzero B; A zero for k>4). Output lands in
//     C-layout: lane(q,nlo) holds H[j = t*16+q*4+r][nbr=nlo] -- gelu applied
//     in-register, repacked as the W2 B-frag under the j-bijection
//     jj=(t&1)*4+r, ch=t>>1; w2f is built with the SAME map so it cancels.
//   MFMA-2: as validated R2-R12 (C' = W2^T x g^T, acc preloaded with b2).
// This deletes the entire per-phase W1 h-stage: 32 pk-FMA + 40 ds_read ->
// 4 MFMA + ~10 VALU. Rationale: R2-R12 pinned at ~41us across all variants;
// per-wave issue bookkeeping says the wall is the summed VALU+DS+trans
// instruction stream, never reduced so far. No LDS left; XCD pinning kept.
// bf16 y/x inputs: +~3e-3 error on top of 0.0625, margin to 0.3275 is ~5x.
__global__ __launch_bounds__(256) void it_kernel(
    const float* __restrict__ y,
    const float* __restrict__ x,
    const float* __restrict__ f_y,
    const float* __restrict__ weights,
    const float* __restrict__ W1,   // [4][64] row-major
    const float* __restrict__ b1,   // [64]
    const float* __restrict__ W2,   // [64][16] row-major
    const float* __restrict__ b2,   // [16]
    const int*   __restrict__ nbr,  // [B][M][K] int32
    float*       __restrict__ out)  // [B][M][16]
{
    const int tid  = threadIdx.x;
    const int lane = tid & 63;
    const int q    = lane >> 4;    // quad 0..3
    const int nlo  = lane & 15;    // neighbor-within-half; also c/m for MFMAs
    // ---- XCD-pinned mapping: batch = blk & 7 (round-robin XCD heuristic) ----
    const int blk   = blockIdx.x;
    const int batch = blk & 7;
    const int pidx  = (blk >> 3) * 4 + (tid >> 6);   // pair index within batch
    const int row0  = __builtin_amdgcn_readfirstlane(batch * M_ + pidx * 2);
    const int bbase = batch * N_;

    // ---- dedup gather: lane g covers (row g>>5, neighbor g&31) ----
    const int r_g = lane >> 5, kk = lane & 31;
    const int raw = nbr[(size_t)(row0 + r_g) * K_ + kk];
    const int vld = raw >= 0;
    const int bn_g = bbase + (vld ? raw : 0);
    const float2 yvg = *(const float2*)(y + (size_t)bn_g * 2);
    const float  wg  = vld ? weights[bn_g] : 0.0f;

    // ---- MFMA-1 A-frags: a1f[t], A[m=nlo (hid=t*16+nlo)][k=q*8+jj] ----
    // k<4: W1[k][t*16+nlo]; k==4: b1[t*16+nlo]; else 0. (q>=1 lanes all 0.)
    short8 a1f[4];
    #pragma unroll
    for (int t = 0; t < 4; ++t) {
        #pragma unroll
        for (int jj = 0; jj < 8; ++jj) {
            const int k = q * 8 + jj;
            float v = 0.0f;
            if (k < 4)       v = W1[k * 64 + t * 16 + nlo];
            else if (k == 4) v = b1[t * 16 + nlo];
            a1f[t][jj] = f2bf(v);
        }
    }

    // ---- W2 A-frag under the j-bijection: w2f[ch][jj] = W2[j][nlo],
    //      j = (ch*2 + (jj>>2))*16 + q*4 + (jj&3) ----
    short8 w2f[2];
    #pragma unroll
    for (int ch = 0; ch < 2; ++ch)
        #pragma unroll
        for (int jj = 0; jj < 8; ++jj) {
            const int j = (ch * 2 + (jj >> 2)) * 16 + q * 4 + (jj & 3);
            w2f[ch][jj] = f2bf(W2[j * DOUT_ + nlo]);
        }

    const floatx4 b2v = *(const floatx4*)(b2 + q * 4);
    const short one_bf = f2bf(1.0f);

    float partial[4] = {0.f, 0.f, 0.f, 0.f};
    #pragma unroll
    for (int ph = 0; ph < 4; ++ph) {
        const int it = ph >> 1, h = ph & 1;
        const int src = ((it << 5) + (h << 4) + nlo) << 2;

        // this phase's f_y gather issued first; MFMA stage covers it
        const int bn = bpermi(src, bn_g);
        const floatx4 fv = *(const floatx4*)(f_y + (size_t)bn * 16 + q * 4);

        // redistribute this phase's y / weight to (q,nlo) layout
        f32x2 yv;
        yv[0] = bpermf(src, yvg.x);
        yv[1] = bpermf(src, yvg.y);
        const float s = bpermf(src, wg);
        const float2 xv = *(const float2*)(x + (size_t)(row0 + it) * 2);  // L1-hot

        // ---- MFMA-1 B-frag: agg column of this lane's neighbor (q=0 only) ----
        short8 bfrag = {0, 0, 0, 0, 0, 0, 0, 0};
        if (q == 0) {
            bfrag[0] = f2bf(yv[0]);
            bfrag[1] = f2bf(yv[1]);
            bfrag[2] = f2bf(xv.x);
            bfrag[3] = f2bf(xv.y);
            bfrag[4] = one_bf;
        }

        // ---- 4x MFMA-1: H tiles, lane(q,nlo) gets H[t*16+q*4+r][nlo] ----
        floatx4 accT[4];
        #pragma unroll
        for (int t = 0; t < 4; ++t) {
            floatx4 z4 = {0.f, 0.f, 0.f, 0.f};
            accT[t] = __builtin_amdgcn_mfma_f32_16x16x32_bf16(a1f[t], bfrag, z4, 0, 0, 0);
        }

        // ---- gelu + repack into W2 B-frag (j-bijection jj=(t&1)*4+r) ----
        short8 hf[2];
        #pragma unroll
        for (int ch = 0; ch < 2; ++ch)
            #pragma unroll
            for (int half = 0; half < 2; ++half) {
                const floatx4 a = accT[ch * 2 + half];
                const f32x2 g0 = gelu2((f32x2){a[0], a[1]});
                const f32x2 g1 = gelu2((f32x2){a[2], a[3]});
                hf[ch][half * 4 + 0] = f2bf(g0[0]);
                hf[ch][half * 4 + 1] = f2bf(g0[1]);
                hf[ch][half * 4 + 2] = f2bf(g1[0]);
                hf[ch][half * 4 + 3] = f2bf(g1[1]);
            }

        // ---- MFMA-2: C' = W2^T x g^T, acc preloaded with b2 ----
        floatx4 acc = b2v;
        acc = __builtin_amdgcn_mfma_f32_16x16x32_bf16(w2f[0], hf[0], acc, 0, 0, 0);
        acc = __builtin_amdgcn_mfma_f32_16x16x32_bf16(w2f[1], hf[1], acc, 0, 0, 0);
        #pragma unroll
        for (int r4 = 0; r4 < 4; ++r4)
            partial[r4] = fmaf(acc[r4], fv[r4] * s, partial[r4]);

        if (h == 1) {   // finished a row: reduce over 16 neighbors, store
            #pragma unroll
            for (int r4 = 0; r4 < 4; ++r4)
                partial[r4] = row16_sum(partial[r4]);
            if (nlo == 15) {
                floatx4 o = {partial[0], partial[1], partial[2], partial[3]};
                *(floatx4*)(out + (size_t)(row0 + it) * DOUT_ + q * 4) = o;
            }
            #pragma unroll
            for (int r4 = 0; r4 < 4; ++r4) partial[r4] = 0.f;
        }
    }
}

extern "C" void kernel_launch(void* const* d_in, const int* in_sizes, int n_in,
                              void* d_out, int out_size, void* d_ws, size_t ws_size,
                              hipStream_t stream) {
    const float* y   = (const float*)d_in[0];
    const float* x   = (const float*)d_in[1];
    const float* f_y = (const float*)d_in[2];
    const float* w   = (const float*)d_in[3];
    const float* W1  = (const float*)d_in[4];
    const float* b1  = (const float*)d_in[5];
    const float* W2  = (const float*)d_in[6];
    const float* b2  = (const float*)d_in[7];
    const int*   nbr = (const int*)d_in[8];
    float* out = (float*)d_out;

    // 4096 blocks: 512 per batch, interleaved so batch = blockIdx % 8 -> XCD
    dim3 grid(B_ * M_ / 8), block(256);
    hipLaunchKernelGGL(it_kernel, grid, block, 0, stream,
                       y, x, f_y, w, W1, b1, W2, b2, nbr, out);
}